// Round 2
// baseline (746.477 us; speedup 1.0000x reference)
//
#include <hip/hip_runtime.h>
#include <stdint.h>

#define NF 64
#define ND 128
#define NPAIR 2016      // 64*63/2
#define THREADS 256
#define WPB 4           // waves per block, one batch per wave

typedef __attribute__((ext_vector_type(4))) float  f32x4;
typedef __attribute__((ext_vector_type(16))) float f32x16;
typedef __attribute__((ext_vector_type(8))) short  s16x8;

// fp32 -> bf16 round-to-nearest-even
__device__ __forceinline__ short f2bf(float v) {
    union { float f; unsigned u; } c; c.f = v;
    unsigned u = c.u;
    u += 0x7fffu + ((u >> 16) & 1u);
    return (short)(u >> 16);
}

// One BATCH per WAVE. No LDS, no barriers: each wave loads its MFMA
// fragments directly from global in fragment order and uses the same
// fragment as both A and B operands (gram is X·X^T and the 32x32x16 A/B
// fragment layouts index identical elements for symmetric input).
//   frag(I) lane l elem e = X[I*32 + (l&31)][kb*16 + (l>>5)*8 + e]
// Lanes l and l+32 read adjacent 32-B halves of the same 64-B line, so
// every fetched line is fully consumed (no over-fetch). 4 independent
// waves/block keep loads in flight continuously (no phase-locking).
__global__ __launch_bounds__(THREADS, 4) void dotint_kernel(
    const float* __restrict__ x, float* __restrict__ out, int nbatch)
{
    const int t    = threadIdx.x;
    const int wave = t >> 6;
    const int lane = t & 63;
    const int lr   = lane & 31;   // row within row-block; col for C
    const int lh   = lane >> 5;   // k-half selector

    const long long g = (long long)blockIdx.x * WPB + wave;
    if (g >= (long long)nbatch) return;   // wave-uniform guard

    // per-lane fragment base pointers (in floats)
    const float* xb = x + g * (NF * ND);
    const float* p0 = xb + lr * ND + lh * 8;          // rows 0..31
    const float* p1 = p0 + 32 * ND;                   // rows 32..63

    f32x16 acc00, acc01, acc11;
    #pragma unroll
    for (int r = 0; r < 16; ++r) { acc00[r] = 0.f; acc01[r] = 0.f; acc11[r] = 0.f; }

    // 1-deep software pipeline over kb = 0..7 (k-step 16 floats = 64 B/row)
    f32x4 a0lo = *(const f32x4*)(p0 + 0);
    f32x4 a0hi = *(const f32x4*)(p0 + 4);
    f32x4 a1lo = *(const f32x4*)(p1 + 0);
    f32x4 a1hi = *(const f32x4*)(p1 + 4);

    #pragma unroll
    for (int kb = 0; kb < 8; ++kb) {
        f32x4 n0lo, n0hi, n1lo, n1hi;
        if (kb < 7) {
            const int ko = (kb + 1) * 16;
            n0lo = *(const f32x4*)(p0 + ko);
            n0hi = *(const f32x4*)(p0 + ko + 4);
            n1lo = *(const f32x4*)(p1 + ko);
            n1hi = *(const f32x4*)(p1 + ko + 4);
        }

        s16x8 f0, f1;
        #pragma unroll
        for (int e = 0; e < 4; ++e) {
            f0[e]     = f2bf(a0lo[e]);
            f0[e + 4] = f2bf(a0hi[e]);
            f1[e]     = f2bf(a1lo[e]);
            f1[e + 4] = f2bf(a1hi[e]);
        }

        acc00 = __builtin_amdgcn_mfma_f32_32x32x16_bf16(f0, f0, acc00, 0, 0, 0);
        acc01 = __builtin_amdgcn_mfma_f32_32x32x16_bf16(f0, f1, acc01, 0, 0, 0);
        acc11 = __builtin_amdgcn_mfma_f32_32x32x16_bf16(f1, f1, acc11, 0, 0, 0);

        a0lo = n0lo; a0hi = n0hi; a1lo = n1lo; a1hi = n1hi;
    }

    // epilogue: C layout col = lane&31, row = (reg&3) + 8*(reg>>2) + 4*lh
    const long long ob = g * (long long)NPAIR;

    #pragma unroll
    for (int r = 0; r < 16; ++r) {
        const int rowInTile = (r & 3) + 8 * (r >> 2) + 4 * lh;
        // tile (0,0)
        {
            const int ii = rowInTile, jj = lr;
            if (jj > ii) {
                const int tri = ii * (127 - ii) / 2 + (jj - ii - 1);
                out[ob + tri] = acc00[r];
            }
        }
        // tile (0,1): ii in 0..31, jj in 32..63 -> always jj > ii
        {
            const int ii = rowInTile, jj = 32 + lr;
            const int tri = ii * (127 - ii) / 2 + (jj - ii - 1);
            out[ob + tri] = acc01[r];
        }
        // tile (1,1)
        {
            const int ii = 32 + rowInTile, jj = 32 + lr;
            if (jj > ii) {
                const int tri = ii * (127 - ii) / 2 + (jj - ii - 1);
                out[ob + tri] = acc11[r];
            }
        }
    }
}

extern "C" void kernel_launch(void* const* d_in, const int* in_sizes, int n_in,
                              void* d_out, int out_size, void* d_ws, size_t ws_size,
                              hipStream_t stream) {
    const float* x = (const float*)d_in[0];
    float* out = (float*)d_out;
    const int B = in_sizes[0] / (NF * ND);   // 16384
    const int grid = (B + WPB - 1) / WPB;    // 4096
    dim3 g(grid), blk(THREADS);
    hipLaunchKernelGGL(dotint_kernel, g, blk, 0, stream, x, out, B);
}

// Round 3
// 708.785 us; speedup vs baseline: 1.0532x; 1.0532x over previous
//
#include <hip/hip_runtime.h>
#include <stdint.h>

#define NF 64
#define ND 128
#define NPAIR 2016      // 64*63/2
#define THREADS 256

typedef __attribute__((ext_vector_type(4))) float  f32x4;
typedef __attribute__((ext_vector_type(16))) float f32x16;
typedef __attribute__((ext_vector_type(4))) short  s16x4;
typedef __attribute__((ext_vector_type(8))) short  s16x8;

// fp32 -> bf16 round-to-nearest-even
__device__ __forceinline__ short f2bf(float v) {
    union { float f; unsigned u; } c; c.f = v;
    unsigned u = c.u;
    u += 0x7fffu + ((u >> 16) & 1u);
    return (short)(u >> 16);
}

// Baseline 707-us structure (1 batch/WG, 16 KiB LDS, launch_bounds(256,8))
// with ONE change: coalesced epilogue. Instead of ~48 exec-masked scattered
// global_store_dword per tile-wave, acc is scattered into LDS (contiguous
// 128-B runs per half-wave -> 2-way bank alias = free), then the 2016-float
// triangle is stored as 504 fully-coalesced float4 by all 4 waves.
__global__ __launch_bounds__(THREADS, 8) void dotint_kernel(
    const float* __restrict__ x, float* __restrict__ out)
{
    __shared__ short lds[NF * ND];   // 8192 bf16 = 16 KiB

    const int t = threadIdx.x;
    const long long b = blockIdx.x;

    // ---------------- stage: coalesced fp32 -> bf16 LDS ----------------
    // 2048 float4 per batch; 2 rounds x 4 float4/thread (keeps live VGPRs low)
    const f32x4* xg = (const f32x4*)x + b * (NF * ND / 4);
    #pragma unroll
    for (int o = 0; o < 2; ++o) {
        f32x4 v[4];
        #pragma unroll
        for (int i = 0; i < 4; ++i)
            v[i] = xg[t + THREADS * (o * 4 + i)];
        #pragma unroll
        for (int i = 0; i < 4; ++i) {
            const int f     = t + THREADS * (o * 4 + i);
            const int row   = f >> 5;            // 32 float4 per row
            const int k4    = f & 31;
            const int kc    = k4 >> 1;
            const int half  = k4 & 1;
            const int chunk = row * 16 + (kc ^ (row & 15));
            s16x4 p;
            p[0] = f2bf(v[i][0]);
            p[1] = f2bf(v[i][1]);
            p[2] = f2bf(v[i][2]);
            p[3] = f2bf(v[i][3]);
            *(s16x4*)&lds[chunk * 8 + half * 4] = p;
        }
    }
    __syncthreads();

    // ---------------- compute: wave w handles gram tile w ----------------
    // tiles: 0:(0,0) 1:(0,1) 2:(1,1); wave 3 idle (stage/store helper)
    const int wave = t >> 6;
    const int lane = t & 63;
    const int lr   = lane & 31;   // row-in-tile for A/B frag, col for C
    const int lh   = lane >> 5;   // k-half selector

    f32x16 acc;
    int I = 0, J = 0;
    if (wave < 3) {
        I = wave >> 1;            // 0,0,1
        J = (wave + 1) >> 1;      // 0,1,1

        #pragma unroll
        for (int r = 0; r < 16; ++r) acc[r] = 0.0f;

        #pragma unroll
        for (int kb = 0; kb < 8; ++kb) {
            const int sw = (kb * 2 + lh) ^ (lr & 15);  // (row&15)==(lr&15)
            s16x8 a  = *(const s16x8*)&lds[((I * 32 + lr) * 16 + sw) * 8];
            s16x8 bb = (I == J) ? a
                     : *(const s16x8*)&lds[((J * 32 + lr) * 16 + sw) * 8];
            acc = __builtin_amdgcn_mfma_f32_32x32x16_bf16(a, bb, acc, 0, 0, 0);
        }
    }

    // ---------------- epilogue: scatter to LDS, store coalesced ----------
    __syncthreads();   // all staging-buffer reads complete before overwrite

    float* lout = (float*)lds;   // 2016 floats = 8064 B, reuses staging LDS
    if (wave < 3) {
        // C layout: col = lane&31, row = (reg&3) + 8*(reg>>2) + 4*lh
        #pragma unroll
        for (int r = 0; r < 16; ++r) {
            const int rowInTile = (r & 3) + 8 * (r >> 2) + 4 * lh;
            const int ii = I * 32 + rowInTile;
            const int jj = J * 32 + lr;
            if (jj > ii) {
                const int tri = ii * (127 - ii) / 2 + (jj - ii - 1);
                lout[tri] = acc[r];   // contiguous 128-B runs per half-wave
            }
        }
    }
    __syncthreads();

    // 504 float4, fully coalesced; out + b*NPAIR is 16-B aligned (2016%4==0)
    f32x4* o4 = (f32x4*)(out + b * (long long)NPAIR);
    const f32x4* l4 = (const f32x4*)lout;
    if (t < 252) {
        o4[t]       = l4[t];
        o4[t + 252] = l4[t + 252];
    }
}

extern "C" void kernel_launch(void* const* d_in, const int* in_sizes, int n_in,
                              void* d_out, int out_size, void* d_ws, size_t ws_size,
                              hipStream_t stream) {
    const float* x = (const float*)d_in[0];
    float* out = (float*)d_out;
    const int B = in_sizes[0] / (NF * ND);   // 16384
    dim3 grid(B), block(THREADS);
    hipLaunchKernelGGL(dotint_kernel, grid, block, 0, stream, x, out);
}